// Round 16
// baseline (363.597 us; speedup 1.0000x reference)
//
#include <hip/hip_runtime.h>
#include <math.h>

#define HB 2
#define HS 2048
#define HHID 2048
#define HH 16
#define HHD 128
#define HRD 64
#define HLD 512
#define HAD 192
#define HM (HB*HS)

static __device__ __constant__ float C1_SCALE_LOG2E = 0.1041175465f;   // (1/sqrt(192)) * log2(e)

typedef unsigned short US;
typedef __attribute__((ext_vector_type(8))) short s8v;   // 8 bf16 (4 VGPRs)
typedef __attribute__((ext_vector_type(4))) float f4v;
typedef __attribute__((ext_vector_type(16))) float f16v;

#if __has_builtin(__builtin_amdgcn_exp2f)
#define EXP2F __builtin_amdgcn_exp2f
#else
#define EXP2F exp2f
#endif

__device__ __forceinline__ US f2b(float f){
  union { float f; unsigned u; } v; v.f = f;
  unsigned r = v.u + 0x7fffu + ((v.u >> 16) & 1u);
  return (US)(r >> 16);
}
__device__ __forceinline__ float b2f(US u){
  union { unsigned u; float f; } v; v.u = ((unsigned)u) << 16; return v.f;
}
__device__ __forceinline__ f4v mfma16(s8v a, s8v b, f4v c){
  return __builtin_amdgcn_mfma_f32_16x16x32_bf16(a, b, c, 0, 0, 0);
}
__device__ __forceinline__ f16v mfma32(s8v a, s8v b, f16v c){
  return __builtin_amdgcn_mfma_f32_32x32x16_bf16(a, b, c, 0, 0, 0);
}
__device__ __forceinline__ void gload_lds16(const void* g, void* l){
  __builtin_amdgcn_global_load_lds((const __attribute__((address_space(1))) void*)g,
                                   (__attribute__((address_space(3))) void*)l, 16, 0, 0);
}

// ---------------- fp32 -> bf16 cast (x) ----------------
__global__ __launch_bounds__(256) void k_cast(const float* __restrict__ in, US* __restrict__ out, int n){
  int i = (blockIdx.x * 256 + threadIdx.x) * 4;
  if (i >= n) return;
  float4 v = *(const float4*)(in + i);
  union { US q[4]; unsigned u[2]; } p;
  p.q[0] = f2b(v.x); p.q[1] = f2b(v.y); p.q[2] = f2b(v.z); p.q[3] = f2b(v.w);
  *(uint2*)(out + i) = make_uint2(p.u[0], p.u[1]);
}

// ---------------- RoPE cos/sin table [S][32] ----------------
__global__ __launch_bounds__(256) void k_rope_tab(float2* __restrict__ tab){
  int idx = blockIdx.x * 256 + threadIdx.x;   // 2048*32 = 65536
  int s = idx >> 5, i = idx & 31;
  float invf = expf(-9.210340371976184f * (float)i / 32.f); // 10000^(-i/32)
  float fr = (float)s * invf;
  tab[idx] = make_float2(cosf(fr), sinf(fr));
}

// ---------------- fused weight prep: all W[K][N] fp32 -> Wt[N][K] bf16 -----------
__global__ __launch_bounds__(256) void k_prep(
    const float* __restrict__ wq, const float* __restrict__ wqr,
    const float* __restrict__ wkvd, const float* __restrict__ wkr,
    const float* __restrict__ wkvu, const float* __restrict__ wo,
    US* __restrict__ wqT, US* __restrict__ wqrT, US* __restrict__ wkvdT,
    US* __restrict__ wkrT, US* __restrict__ wkvuT, US* __restrict__ woT)
{
  __shared__ float t[32][33];
  int bid = blockIdx.x;
  const float* W; US* Wt; int K, N, nx; int womap = 0;
  if (bid < 4096){                       W = wq;   Wt = wqT;   K = 2048; N = 2048; nx = 64; }
  else if (bid < 6144){ bid -= 4096;     W = wqr;  Wt = wqrT;  K = 2048; N = 1024; nx = 32; }
  else if (bid < 7168){ bid -= 6144;     W = wkvd; Wt = wkvdT; K = 2048; N = 512;  nx = 16; }
  else if (bid < 7296){ bid -= 7168;     W = wkr;  Wt = wkrT;  K = 2048; N = 64;   nx = 2;  }
  else if (bid < 9344){ bid -= 7296;     W = wkvu; Wt = wkvuT; K = 512;  N = 4096; nx = 128;}
  else               { bid -= 9344;      W = wo;   Wt = woT;   K = 2048; N = 2048; nx = 64; womap = 1; }
  int n0 = (bid % nx) * 32, k0 = (bid / nx) * 32;
  int tx = threadIdx.x & 31, ty = threadIdx.x >> 5;
  #pragma unroll
  for (int r = 0; r < 32; r += 8){
    int k = k0 + ty + r;
    int sk = womap ? ((k >> 7) * 192 + (k & 127)) : k;   // wo row-gather: skip V-pad rows
    t[ty + r][tx] = W[(size_t)sk * N + n0 + tx];
  }
  __syncthreads();
  #pragma unroll
  for (int r = 0; r < 32; r += 8){
    Wt[(size_t)(n0 + ty + r) * K + k0 + tx] = f2b(t[tx][ty + r]);
  }
}

// ---------------- bf16 transpose V [bh][s][d] -> [bh][d][s] ----------------
__global__ __launch_bounds__(256) void k_transpose_v(const US* __restrict__ v, US* __restrict__ vT){
  __shared__ US t[32][33];
  int bh = blockIdx.z;
  int s0 = blockIdx.x * 32, d0 = blockIdx.y * 32;
  const US* src = v + (size_t)bh * HS * HHD;
  US* dst = vT + (size_t)bh * HHD * HS;
  int tx = threadIdx.x, ty = threadIdx.y;
  #pragma unroll
  for (int r = 0; r < 32; r += 8)
    t[ty + r][tx] = src[(size_t)(s0 + ty + r) * HHD + d0 + tx];
  __syncthreads();
  #pragma unroll
  for (int r = 0; r < 32; r += 8)
    dst[(size_t)(d0 + ty + r) * HS + s0 + tx] = t[tx][ty + r];
}

// ---------------- GEMM v2 (2-phase, 128x128, 4 waves, BK=64) — kept for wo ----
template<int EPI>
__global__ __launch_bounds__(256, 2) void k_gemm2(
    const US* __restrict__ A, const US* __restrict__ Bt,
    void* __restrict__ out0, void* __restrict__ out1,
    void* __restrict__ out2, void* __restrict__ out3,
    int Kdim, int Ndim)
{
  __shared__ US As[2][128 * 64];
  __shared__ US Bs[2][128 * 64];
  const int tid = threadIdx.x;
  const int lane = tid & 63, w = tid >> 6;
  const int r15 = lane & 15, kh = lane >> 4;
  const int gx = gridDim.x;
  const int flat = blockIdx.y * gx + blockIdx.x;
  const int cpx = (gx * gridDim.y) >> 3;
  const int swz = (flat & 7) * cpx + (flat >> 3);
  const int m0 = (swz / gx) * 128, n0 = (swz % gx) * 128;
  const int wm = (w >> 1) * 64, wn = (w & 1) * 64;
  const int rsw = (r15 & 7) << 4;     // frag-read XOR (row&7 == r15&7)
  f4v acc[4][4] = {};

  auto STAGE = [&](int k0, int bb){
    #pragma unroll
    for (int j = 0; j < 4; ++j){       // A: 128 rows x 8 16B-chunks = 1024
      int c = j * 256 + tid;
      int row = c >> 3, colD = (c & 7) * 16;
      gload_lds16((const char*)A + ((size_t)(m0 + row) * Kdim + k0) * 2 + (colD ^ ((row & 7) << 4)),
                  (char*)As[bb] + c * 16);
    }
    #pragma unroll
    for (int j = 0; j < 4; ++j){       // B: 128 rows x 8 chunks
      int c = j * 256 + tid;
      int row = c >> 3, colD = (c & 7) * 16;
      gload_lds16((const char*)Bt + ((size_t)(n0 + row) * Kdim + k0) * 2 + (colD ^ ((row & 7) << 4)),
                  (char*)Bs[bb] + c * 16);
    }
  };

  const int nk = Kdim >> 6;
  STAGE(0, 0);
  for (int t = 0; t < nk; ++t){
    if (t + 1 < nk){
      STAGE((t + 1) * 64, (t + 1) & 1);
      asm volatile("s_waitcnt vmcnt(8)" ::: "memory");
    } else {
      asm volatile("s_waitcnt vmcnt(0)" ::: "memory");
    }
    __builtin_amdgcn_s_barrier();
    __builtin_amdgcn_sched_barrier(0);
    const char* AB = (const char*)As[t & 1];
    const char* BB = (const char*)Bs[t & 1];
    #pragma unroll
    for (int ks = 0; ks < 2; ++ks){
      s8v af[4];
      #pragma unroll
      for (int mi = 0; mi < 4; ++mi)
        af[mi] = *(const s8v*)(AB + (wm + mi * 16 + r15) * 128 + ((ks * 64 + kh * 16) ^ rsw));
      #pragma unroll
      for (int ni = 0; ni < 4; ++ni){
        s8v bf = *(const s8v*)(BB + (wn + ni * 16 + r15) * 128 + ((ks * 64 + kh * 16) ^ rsw));
        #pragma unroll
        for (int mi = 0; mi < 4; ++mi)
          acc[mi][ni] = mfma16(af[mi], bf, acc[mi][ni]);
      }
    }
    __builtin_amdgcn_s_barrier();
  }

  #pragma unroll
  for (int mi = 0; mi < 4; ++mi){
    #pragma unroll
    for (int ni = 0; ni < 4; ++ni){
      #pragma unroll
      for (int j = 0; j < 4; ++j){
        float v = acc[mi][ni][j];
        int m = m0 + wm + mi * 16 + kh * 4 + j;
        int n = n0 + wn + ni * 16 + r15;
        if (EPI == 4){ // f32 final output [M][HID]
          ((float*)out0)[(size_t)m * HHID + n] = v;
        }
      }
    }
  }
}

// ---------------- GEMM v3: 256x256 4-phase template (T3+T4+T5) ----------------
template<int EPI>
__global__ __launch_bounds__(512, 1) void k_gemm8(
    const US* __restrict__ A, const US* __restrict__ Bt,
    void* __restrict__ out0, void* __restrict__ out1,
    void* __restrict__ out2, void* __restrict__ out3,
    int Kdim, int Ndim)
{
  __shared__ US As[2][256 * 64];   // 64 KB
  __shared__ US Bs[2][256 * 64];   // 64 KB
  const int tid = threadIdx.x, lane = tid & 63, w = tid >> 6;
  const int r15 = lane & 15, kh = lane >> 4;
  const int gx = gridDim.x;
  const int flat = blockIdx.y * gx + blockIdx.x;
  const int cpx = (gx * gridDim.y) >> 3;
  const int swz = (flat & 7) * cpx + (flat >> 3);
  const int m0 = (swz / gx) * 256, n0 = (swz % gx) * 256;
  const int wmL = (w >> 2) * 128, wnL = (w & 3) * 64;
  const int rsw = (r15 & 7) << 4;
  const int nt = Kdim >> 6;

  f4v acc[8][4] = {};
  s8v bf[4][2];

  auto STAGE_A = [&](int t, int par, int half){   // 2 gloads/thread
    int tt = (t < nt) ? t : (nt - 1);
    #pragma unroll
    for (int j = 0; j < 2; ++j){
      int c = j * 512 + tid;
      int row = c >> 3, ch = c & 7;
      gload_lds16((const char*)A + ((size_t)(m0 + half * 128 + row) * Kdim + tt * 64) * 2 + ((ch * 16) ^ ((row & 7) << 4)),
                  (char*)As[par] + half * 16384 + c * 16);
    }
  };
  auto STAGE_B = [&](int t, int par, int half){
    int tt = (t < nt) ? t : (nt - 1);
    #pragma unroll
    for (int j = 0; j < 2; ++j){
      int c = j * 512 + tid;
      int row = c >> 3, ch = c & 7;
      gload_lds16((const char*)Bt + ((size_t)(n0 + half * 128 + row) * Kdim + tt * 64) * 2 + ((ch * 16) ^ ((row & 7) << 4)),
                  (char*)Bs[par] + half * 16384 + c * 16);
    }
  };

  // ---- prologue: B(t0), A(t0), B(t1) -> queue 12 loads; land first 8
  STAGE_B(0, 0, 0); STAGE_B(0, 0, 1);
  STAGE_A(0, 0, 0); STAGE_A(0, 0, 1);
  STAGE_B(1, 1, 0); STAGE_B(1, 1, 1);
  asm volatile("s_waitcnt vmcnt(4)" ::: "memory");
  __builtin_amdgcn_s_barrier();

  const int nk2 = nt >> 1;
  for (int i = 0; i < nk2; ++i){
    const int t0 = 2 * i, t1 = 2 * i + 1;
    #pragma unroll
    for (int par = 0; par < 2; ++par){
      #pragma unroll
      for (int q = 0; q < 2; ++q){
        if (q == 0){
          #pragma unroll
          for (int ni = 0; ni < 4; ++ni)
            #pragma unroll
            for (int kk = 0; kk < 2; ++kk)
              bf[ni][kk] = *(const s8v*)((const char*)Bs[par] + (wnL + ni * 16 + r15) * 128 + ((kk * 64 + kh * 16) ^ rsw));
        }
        s8v af[4][2];
        #pragma unroll
        for (int m2 = 0; m2 < 4; ++m2)
          #pragma unroll
          for (int kk = 0; kk < 2; ++kk)
            af[m2][kk] = *(const s8v*)((const char*)As[par] + (wmL + (q * 4 + m2) * 16 + r15) * 128 + ((kk * 64 + kh * 16) ^ rsw));
        if (par == 0 && q == 0){ STAGE_A(t1, 1, 0); STAGE_A(t1, 1, 1); }
        else if (par == 0 && q == 1){ STAGE_B(t0 + 2, 0, 0); STAGE_B(t0 + 2, 0, 1); }
        else if (par == 1 && q == 0){ STAGE_A(t0 + 2, 0, 0); STAGE_A(t0 + 2, 0, 1); }
        else                        { STAGE_B(t1 + 2, 1, 0); STAGE_B(t1 + 2, 1, 1); }
        __builtin_amdgcn_s_barrier();
        __builtin_amdgcn_sched_barrier(0);
        __builtin_amdgcn_s_setprio(1);
        #pragma unroll
        for (int m2 = 0; m2 < 4; ++m2)
          #pragma unroll
          for (int ni = 0; ni < 4; ++ni)
            #pragma unroll
            for (int kk = 0; kk < 2; ++kk)
              acc[q * 4 + m2][ni] = mfma16(af[m2][kk], bf[ni][kk], acc[q * 4 + m2][ni]);
        __builtin_amdgcn_s_setprio(0);
        if (q == 1){ asm volatile("s_waitcnt vmcnt(4)" ::: "memory"); }
        __builtin_amdgcn_s_barrier();
      }
    }
  }

  // ---- epilogue
  #pragma unroll
  for (int mi = 0; mi < 8; ++mi){
    #pragma unroll
    for (int ni = 0; ni < 4; ++ni){
      #pragma unroll
      for (int j = 0; j < 4; ++j){
        float v = acc[mi][ni][j];
        int m = m0 + wmL + mi * 16 + kh * 4 + j;
        int n = n0 + wnL + ni * 16 + r15;
        if (EPI == 3){ // kv: k_nope -> knbuf [bh][s][128], v -> vbuf
          int b = m >> 11, s = m & 2047;
          int h = n >> 8, r = n & 255;
          if (r < 128)
            ((US*)out0)[((size_t)(b * HH + h) * HS + s) * HHD + r] = f2b(v);
          else
            ((US*)out1)[((size_t)(b * HH + h) * HS + s) * HHD + (r - 128)] = f2b(v);
        } else { // EPI==5: merged: q_nope | q_rope | latent | k_rope
          int b = m >> 11, s = m & 2047;
          if (n < 2048){
            int h = n >> 7, d = n & 127;
            ((US*)out0)[((size_t)(b * HH + h) * HS + s) * HAD + d] = f2b(v);
          } else if (n < 3072){
            int dd2 = n - 2048;
            int h = dd2 >> 6, dd = dd2 & 63;
            float partner = acc[mi][ni ^ 2][j];
            float2 cs = ((const float2*)out1)[s * 32 + (dd & 31)];
            float o = (dd < 32) ? (v * cs.x - partner * cs.y) : (v * cs.x + partner * cs.y);
            ((US*)out0)[((size_t)(b * HH + h) * HS + s) * HAD + HHD + dd] = f2b(o);
          } else if (n < 3584){
            ((US*)out2)[(size_t)m * HLD + (n - 3072)] = f2b(v);
          } else if (n < 3648){ // k_rope: RoPE, ONE shared copy
            int dd = n - 3584;
            float partner = acc[mi][ni ^ 2][j];
            float2 cs = ((const float2*)out1)[s * 32 + (dd & 31)];
            float o = (dd < 32) ? (v * cs.x - partner * cs.y) : (v * cs.x + partner * cs.y);
            ((US*)out3)[(size_t)m * HRD + dd] = f2b(o);
          } // n >= 3648: pad, drop
        }
      }
    }
  }
}

// ---------------- causal flash attention: KVBLK=32, 40KB LDS, 3 blocks/CU ----
// 4 waves x 32 q = 128 q/block, 512 blocks, LPT. K+V double-buffered at
// KVBLK=32 (K 2x12KB + V 2x8KB = 40KB) -> 3 blocks/CU co-resident TLP hides
// the doubled per-tile sync. Counted vmcnt(5). V rows are 64B -> V swizzle
// (d&3)<<4 (row-contained); K rows 384B keep (row&7)<<4.
__global__ __launch_bounds__(256, 3) void k_attn(
    const US* __restrict__ qbuf, const US* __restrict__ knbuf,
    const US* __restrict__ krbuf, const US* __restrict__ vT,
    US* __restrict__ attnb)
{
  __shared__ US Ks[2][32 * 192];   // [kv][192] packed, byte ^= (kv&7)<<4   (12 KB x2)
  __shared__ US Vs[2][128 * 32];   // [d][32]  packed, byte ^= (d&3)<<4     (8 KB x2)

  const int tid = threadIdx.x, lane = tid & 63, w = tid >> 6;
  const int l31 = lane & 31, hi = lane >> 5;
  const int bid = blockIdx.x;           // bh = bid&31 -> XCD = bh&7 (K/V L2 locality)
  const int bh = bid & 31, b = bh >> 4, head = bh & 15;
  // LPT: first 256 blocks long (u=15..8), second 256 short (u=0..7)
  const int u = (bid < 256) ? (15 - (bid >> 5)) : ((bid - 256) >> 5);
  const int q0 = u * 128;
  const int qw0 = q0 + w * 32;                       // wave's first q row
  const int qrow = qw0 + l31;                        // this lane's q row
  const int swk = (l31 & 7) << 4;                    // K-read XOR
  const int swv = (l31 & 3) << 4;                    // V-read XOR (64B rows)

  const char* qb = (const char*)(qbuf + (size_t)bh * HS * HAD);
  const char* kn = (const char*)(knbuf + (size_t)bh * HS * HHD);
  const char* kr = (const char*)(krbuf + (size_t)b * HS * HRD);
  const char* vb = (const char*)(vT   + (size_t)bh * HHD * HS);

  // Q fragments (B-operand): col = lane&31 = q, k = hi*8 + j
  s8v qf[12];
  {
    const char* qr = qb + (size_t)qrow * 384;
    #pragma unroll
    for (int ks = 0; ks < 12; ++ks)
      qf[ks] = *(const s8v*)(qr + ks * 32 + hi * 16);
  }

  // stage one 32-KV tile into buffer bb (5 global_load_lds per lane)
  auto STAGE = [&](int tt, int bb){
    const int k0s = tt * 32;
    #pragma unroll
    for (int j = 0; j < 3; ++j){               // K: 32 rows x 24 16B-chunks = 768
      int c = j * 256 + tid;
      int row = c / 24, cc = c - row * 24;
      int xsw = (row & 7) << 4;
      const char* src = (cc < 16)
          ? kn + (size_t)(k0s + row) * 256 + ((cc * 16) ^ xsw)
          : kr + (size_t)(k0s + row) * 128 + (((cc - 16) * 16) ^ xsw);
      gload_lds16(src, (char*)Ks[bb] + (j * 4 + w) * 1024);
    }
    #pragma unroll
    for (int j = 0; j < 2; ++j){               // V^T: 128 rows x 4 chunks = 512
      int c = j * 256 + tid;
      int d = c >> 2, colD = (c & 3) * 16;
      gload_lds16(vb + (size_t)d * (HS * 2) + (size_t)k0s * 2 + (colD ^ ((d & 3) << 4)),
                  (char*)Vs[bb] + (j * 4 + w) * 1024);
    }
  };

  f16v acc_o[4] = {};       // O: rows q=crow(r,hi), cols d = db*32 + l31
  float mraw = -3e38f, lsum = 0.f;

  const int nt = (q0 + 128) >> 5;
  STAGE(0, 0);
  for (int t = 0; t < nt; ++t){
    if (t + 1 < nt){
      STAGE(t + 1, (t + 1) & 1);
      asm volatile("s_waitcnt vmcnt(5)" ::: "memory");   // tile t landed; t+1 in flight
    } else {
      asm volatile("s_waitcnt vmcnt(0)" ::: "memory");
    }
    __builtin_amdgcn_s_barrier();
    __builtin_amdgcn_sched_barrier(0);

    const int k0 = t * 32;
    if (k0 <= qw0 + 31){     // wave-uniform: skip fully-masked tiles
      const char* KB = (const char*)Ks[t & 1];
      const char* VB = (const char*)Vs[t & 1];
      // ---- QK^T (swapped): S^T[kv][q], A=K from LDS, B=Q regs
      f16v sacc = {};
      __builtin_amdgcn_s_setprio(1);
      #pragma unroll
      for (int ks = 0; ks < 12; ++ks){
        s8v kf = *(const s8v*)(KB + l31 * 384 + ((ks * 32 + hi * 16) ^ swk));
        sacc = mfma32(kf, qf[ks], sacc);
      }
      __builtin_amdgcn_s_setprio(0);

      // ---- mask + tile max (in-lane; lane owns q-row qrow)
      const bool need_mask = (k0 + 31 > qrow);
      float mx = -3e38f;
      #pragma unroll
      for (int r = 0; r < 16; ++r){
        float s = sacc[r];
        if (need_mask){
          int kv = k0 + (r & 3) + 8 * (r >> 2) + 4 * hi;
          if (kv > qrow) s = -3e38f;
          sacc[r] = s;
        }
        mx = fmaxf(mx, s);
      }
      mx = fmaxf(mx, __shfl_xor(mx, 32));

      // ---- defer-max (T13)
      float scl = 1.0f;
      if (__any(mx > mraw + 76.8f)){           // 76.8 = 8 / (SCALE*log2e)
        float mnew = fmaxf(mraw, mx);
        scl = EXP2F((mraw - mnew) * C1_SCALE_LOG2E);
        mraw = mnew;
        #pragma unroll
        for (int r = 0; r < 16; ++r){
          float sb = __shfl(scl, (r & 3) + 8 * (r >> 2) + 4 * hi);
          #pragma unroll
          for (int db = 0; db < 4; ++db)
            acc_o[db][r] *= sb;
        }
      }

      // ---- exp + row-sum
      float m2 = mraw * C1_SCALE_LOG2E;
      float rs = 0.f;
      #pragma unroll
      for (int r = 0; r < 16; ++r){
        float p = EXP2F(fmaf(sacc[r], C1_SCALE_LOG2E, -m2));
        sacc[r] = p;
        rs += p;
      }
      rs += __shfl_xor(rs, 32);
      lsum = lsum * scl + rs;

      // ---- P -> bf16 A-frags in-register: 8 cvt_pk + 4 permlane32_swap
      union PU { s8v v; unsigned u[4]; } pa[2];
      #pragma unroll
      for (int g = 0; g < 2; ++g){
        unsigned a0, a1, b0, b1;
        const int rb = g * 8;
        asm("v_cvt_pk_bf16_f32 %0, %1, %2" : "=v"(a0) : "v"(sacc[rb + 0]), "v"(sacc[rb + 1]));
        asm("v_cvt_pk_bf16_f32 %0, %1, %2" : "=v"(a1) : "v"(sacc[rb + 2]), "v"(sacc[rb + 3]));
        asm("v_cvt_pk_bf16_f32 %0, %1, %2" : "=v"(b0) : "v"(sacc[rb + 4]), "v"(sacc[rb + 5]));
        asm("v_cvt_pk_bf16_f32 %0, %1, %2" : "=v"(b1) : "v"(sacc[rb + 6]), "v"(sacc[rb + 7]));
        asm("v_permlane32_swap_b32 %0, %1" : "+v"(a0), "+v"(b0));
        asm("v_permlane32_swap_b32 %0, %1" : "+v"(a1), "+v"(b1));
        pa[g].u[0] = a0; pa[g].u[1] = a1;
        pa[g].u[2] = b0; pa[g].u[3] = b1;
      }

      // ---- PV: O += P * V, B-frags from swizzled Vs (64B rows)
      __builtin_amdgcn_s_setprio(1);
      #pragma unroll
      for (int ks2 = 0; ks2 < 2; ++ks2){
        #pragma unroll
        for (int db = 0; db < 4; ++db){
          s8v vf = *(const s8v*)(VB + (db * 32 + l31) * 64 + ((ks2 * 32 + hi * 16) ^ swv));
          acc_o[db] = mfma32(pa[ks2].v, vf, acc_o[db]);
        }
      }
      __builtin_amdgcn_s_setprio(0);
    }
    __builtin_amdgcn_s_barrier();
  }

  // ---- epilogue: normalize by 1/l (broadcast to crow layout via shfl), store
  float linv = 1.0f / lsum;
  #pragma unroll
  for (int r = 0; r < 16; ++r){
    int crow = (r & 3) + 8 * (r >> 2) + 4 * hi;
    float lb = __shfl(linv, crow);
    int qq = qw0 + crow;
    US* dst = attnb + (size_t)(b * HS + qq) * (HH * HHD) + head * HHD;
    #pragma unroll
    for (int db = 0; db < 4; ++db)
      dst[db * 32 + l31] = f2b(acc_o[db][r] * lb);
  }
}

extern "C" void kernel_launch(void* const* d_in, const int* in_sizes, int n_in,
                              void* d_out, int out_size, void* d_ws, size_t ws_size,
                              hipStream_t stream)
{
  (void)in_sizes; (void)n_in; (void)out_size; (void)ws_size;
  const float* x        = (const float*)d_in[0];
  const float* wq       = (const float*)d_in[1];
  const float* wq_rope  = (const float*)d_in[2];
  const float* wkv_down = (const float*)d_in[3];
  const float* wkv_up   = (const float*)d_in[4];
  const float* wk_rope  = (const float*)d_in[5];
  const float* wo       = (const float*)d_in[6];

  char* ws = (char*)d_ws;
  size_t off = 0;
  auto alloc = [&](size_t bytes)->void*{ void* p = ws + off; off += (bytes + 255) & ~(size_t)255; return p; };

  US* xb     = (US*)alloc((size_t)HM * HHID * 2);        // 16 MB (aliased as attnb later)
  // wqT/wqrT/wkvdT/wkrT/pad contiguous -> one merged B^T [3840][2048] (incl 192 pad rows)
  US* wqT    = (US*)alloc((size_t)2048 * 2048 * 2);
  US* wqrT   = (US*)alloc((size_t)1024 * 2048 * 2);
  US* wkvdT  = (US*)alloc((size_t)512 * 2048 * 2);
  US* wkrT   = (US*)alloc((size_t)64 * 2048 * 2);
  US* wkrPad = (US*)alloc((size_t)192 * 2048 * 2);       // zeroed pad rows 3648..3839
  US* wkvuT  = (US*)alloc((size_t)4096 * 512 * 2);
  US* woT    = (US*)alloc((size_t)2048 * 2048 * 2);
  US* qbuf   = (US*)alloc((size_t)32 * HS * HAD * 2);
  US* knbuf  = (US*)alloc((size_t)32 * HS * HHD * 2);    // k_nope per-head
  US* krbuf  = (US*)alloc((size_t)HB * HS * HRD * 2);    // k_rope shared (0.5 MB)
  US* vbuf   = (US*)alloc((size_t)32 * HS * HHD * 2);
  US* vTb    = (US*)alloc((size_t)32 * HS * HHD * 2);
  US* latent = (US*)alloc((size_t)HM * HLD * 2);
  float2* tab = (float2*)alloc((size_t)HS * 32 * 8);
  US* attnb = xb;   // xb dead after merged projection; reuse

  dim3 tb(256);
  dim3 t328(32, 8);

  hipMemsetAsync(wkrPad, 0, (size_t)192 * 2048 * 2, stream);
  k_cast<<<dim3(8192), tb, 0, stream>>>(x, xb, HM * HHID);
  k_rope_tab<<<dim3(256), tb, 0, stream>>>(tab);
  // fused weight prep: 4096+2048+1024+128+2048+4096 = 13440 tile-blocks
  k_prep<<<dim3(13440), tb, 0, stream>>>(wq, wq_rope, wkv_down, wk_rope, wkv_up, wo,
                                         wqT, wqrT, wkvdT, wkrT, wkvuT, woT);

  // merged x-projections: [4096,2048] x [3840,2048]^T (4-phase 256^2)
  k_gemm8<5><<<dim3(15, 16), dim3(512), 0, stream>>>(xb, wqT, (void*)qbuf, (void*)tab, (void*)latent, (void*)krbuf, 2048, 3840);
  // kv-up: [4096,512] x [4096,512]^T (4-phase 256^2)
  k_gemm8<3><<<dim3(16, 16), dim3(512), 0, stream>>>(latent, wkvuT, (void*)knbuf, (void*)vbuf, (void*)nullptr, (void*)nullptr, 512, 4096);
  k_transpose_v<<<dim3(64, 4, 32), t328, 0, stream>>>(vbuf, vTb);
  k_attn<<<dim3(512), tb, 0, stream>>>(qbuf, knbuf, krbuf, vTb, attnb);
  k_gemm2<4><<<dim3(16, 32), tb, 0, stream>>>(attnb, woT, d_out, (void*)nullptr, (void*)nullptr, (void*)nullptr, 2048, 2048);
}

// Round 17
// 275.644 us; speedup vs baseline: 1.3191x; 1.3191x over previous
//
#include <hip/hip_runtime.h>
#include <math.h>

#define HB 2
#define HS 2048
#define HHID 2048
#define HH 16
#define HHD 128
#define HRD 64
#define HLD 512
#define HAD 192
#define HM (HB*HS)

static __device__ __constant__ float C1_SCALE_LOG2E = 0.1041175465f;   // (1/sqrt(192)) * log2(e)

typedef unsigned short US;
typedef __attribute__((ext_vector_type(8))) short s8v;   // 8 bf16 (4 VGPRs)
typedef __attribute__((ext_vector_type(4))) float f4v;
typedef __attribute__((ext_vector_type(16))) float f16v;

#if __has_builtin(__builtin_amdgcn_exp2f)
#define EXP2F __builtin_amdgcn_exp2f
#else
#define EXP2F exp2f
#endif

__device__ __forceinline__ US f2b(float f){
  union { float f; unsigned u; } v; v.f = f;
  unsigned r = v.u + 0x7fffu + ((v.u >> 16) & 1u);
  return (US)(r >> 16);
}
__device__ __forceinline__ float b2f(US u){
  union { unsigned u; float f; } v; v.u = ((unsigned)u) << 16; return v.f;
}
__device__ __forceinline__ f4v mfma16(s8v a, s8v b, f4v c){
  return __builtin_amdgcn_mfma_f32_16x16x32_bf16(a, b, c, 0, 0, 0);
}
__device__ __forceinline__ f16v mfma32(s8v a, s8v b, f16v c){
  return __builtin_amdgcn_mfma_f32_32x32x16_bf16(a, b, c, 0, 0, 0);
}
__device__ __forceinline__ void gload_lds16(const void* g, void* l){
  __builtin_amdgcn_global_load_lds((const __attribute__((address_space(1))) void*)g,
                                   (__attribute__((address_space(3))) void*)l, 16, 0, 0);
}

// ---------------- fp32 -> bf16 cast (x) ----------------
__global__ __launch_bounds__(256) void k_cast(const float* __restrict__ in, US* __restrict__ out, int n){
  int i = (blockIdx.x * 256 + threadIdx.x) * 4;
  if (i >= n) return;
  float4 v = *(const float4*)(in + i);
  union { US q[4]; unsigned u[2]; } p;
  p.q[0] = f2b(v.x); p.q[1] = f2b(v.y); p.q[2] = f2b(v.z); p.q[3] = f2b(v.w);
  *(uint2*)(out + i) = make_uint2(p.u[0], p.u[1]);
}

// ---------------- RoPE cos/sin table [S][32] ----------------
__global__ __launch_bounds__(256) void k_rope_tab(float2* __restrict__ tab){
  int idx = blockIdx.x * 256 + threadIdx.x;   // 2048*32 = 65536
  int s = idx >> 5, i = idx & 31;
  float invf = expf(-9.210340371976184f * (float)i / 32.f); // 10000^(-i/32)
  float fr = (float)s * invf;
  tab[idx] = make_float2(cosf(fr), sinf(fr));
}

// ---------------- fused weight prep: all W[K][N] fp32 -> Wt[N][K] bf16 -----------
__global__ __launch_bounds__(256) void k_prep(
    const float* __restrict__ wq, const float* __restrict__ wqr,
    const float* __restrict__ wkvd, const float* __restrict__ wkr,
    const float* __restrict__ wkvu, const float* __restrict__ wo,
    US* __restrict__ wqT, US* __restrict__ wqrT, US* __restrict__ wkvdT,
    US* __restrict__ wkrT, US* __restrict__ wkvuT, US* __restrict__ woT)
{
  __shared__ float t[32][33];
  int bid = blockIdx.x;
  const float* W; US* Wt; int K, N, nx; int womap = 0;
  if (bid < 4096){                       W = wq;   Wt = wqT;   K = 2048; N = 2048; nx = 64; }
  else if (bid < 6144){ bid -= 4096;     W = wqr;  Wt = wqrT;  K = 2048; N = 1024; nx = 32; }
  else if (bid < 7168){ bid -= 6144;     W = wkvd; Wt = wkvdT; K = 2048; N = 512;  nx = 16; }
  else if (bid < 7296){ bid -= 7168;     W = wkr;  Wt = wkrT;  K = 2048; N = 64;   nx = 2;  }
  else if (bid < 9344){ bid -= 7296;     W = wkvu; Wt = wkvuT; K = 512;  N = 4096; nx = 128;}
  else               { bid -= 9344;      W = wo;   Wt = woT;   K = 2048; N = 2048; nx = 64; womap = 1; }
  int n0 = (bid % nx) * 32, k0 = (bid / nx) * 32;
  int tx = threadIdx.x & 31, ty = threadIdx.x >> 5;
  #pragma unroll
  for (int r = 0; r < 32; r += 8){
    int k = k0 + ty + r;
    int sk = womap ? ((k >> 7) * 192 + (k & 127)) : k;   // wo row-gather: skip V-pad rows
    t[ty + r][tx] = W[(size_t)sk * N + n0 + tx];
  }
  __syncthreads();
  #pragma unroll
  for (int r = 0; r < 32; r += 8){
    Wt[(size_t)(n0 + ty + r) * K + k0 + tx] = f2b(t[tx][ty + r]);
  }
}

// ---------------- bf16 transpose V [bh][s][d] -> [bh][d][s] ----------------
__global__ __launch_bounds__(256) void k_transpose_v(const US* __restrict__ v, US* __restrict__ vT){
  __shared__ US t[32][33];
  int bh = blockIdx.z;
  int s0 = blockIdx.x * 32, d0 = blockIdx.y * 32;
  const US* src = v + (size_t)bh * HS * HHD;
  US* dst = vT + (size_t)bh * HHD * HS;
  int tx = threadIdx.x, ty = threadIdx.y;
  #pragma unroll
  for (int r = 0; r < 32; r += 8)
    t[ty + r][tx] = src[(size_t)(s0 + ty + r) * HHD + d0 + tx];
  __syncthreads();
  #pragma unroll
  for (int r = 0; r < 32; r += 8)
    dst[(size_t)(d0 + ty + r) * HS + s0 + tx] = t[tx][ty + r];
}

// ---------------- GEMM v2 (2-phase, 128x128, 4 waves, BK=64) — kept for wo ----
template<int EPI>
__global__ __launch_bounds__(256, 2) void k_gemm2(
    const US* __restrict__ A, const US* __restrict__ Bt,
    void* __restrict__ out0, void* __restrict__ out1,
    void* __restrict__ out2, void* __restrict__ out3,
    int Kdim, int Ndim)
{
  __shared__ US As[2][128 * 64];
  __shared__ US Bs[2][128 * 64];
  const int tid = threadIdx.x;
  const int lane = tid & 63, w = tid >> 6;
  const int r15 = lane & 15, kh = lane >> 4;
  const int gx = gridDim.x;
  const int flat = blockIdx.y * gx + blockIdx.x;
  const int cpx = (gx * gridDim.y) >> 3;
  const int swz = (flat & 7) * cpx + (flat >> 3);
  const int m0 = (swz / gx) * 128, n0 = (swz % gx) * 128;
  const int wm = (w >> 1) * 64, wn = (w & 1) * 64;
  const int rsw = (r15 & 7) << 4;     // frag-read XOR (row&7 == r15&7)
  f4v acc[4][4] = {};

  auto STAGE = [&](int k0, int bb){
    #pragma unroll
    for (int j = 0; j < 4; ++j){       // A: 128 rows x 8 16B-chunks = 1024
      int c = j * 256 + tid;
      int row = c >> 3, colD = (c & 7) * 16;
      gload_lds16((const char*)A + ((size_t)(m0 + row) * Kdim + k0) * 2 + (colD ^ ((row & 7) << 4)),
                  (char*)As[bb] + c * 16);
    }
    #pragma unroll
    for (int j = 0; j < 4; ++j){       // B: 128 rows x 8 chunks
      int c = j * 256 + tid;
      int row = c >> 3, colD = (c & 7) * 16;
      gload_lds16((const char*)Bt + ((size_t)(n0 + row) * Kdim + k0) * 2 + (colD ^ ((row & 7) << 4)),
                  (char*)Bs[bb] + c * 16);
    }
  };

  const int nk = Kdim >> 6;
  STAGE(0, 0);
  for (int t = 0; t < nk; ++t){
    if (t + 1 < nk){
      STAGE((t + 1) * 64, (t + 1) & 1);
      asm volatile("s_waitcnt vmcnt(8)" ::: "memory");
    } else {
      asm volatile("s_waitcnt vmcnt(0)" ::: "memory");
    }
    __builtin_amdgcn_s_barrier();
    __builtin_amdgcn_sched_barrier(0);
    const char* AB = (const char*)As[t & 1];
    const char* BB = (const char*)Bs[t & 1];
    #pragma unroll
    for (int ks = 0; ks < 2; ++ks){
      s8v af[4];
      #pragma unroll
      for (int mi = 0; mi < 4; ++mi)
        af[mi] = *(const s8v*)(AB + (wm + mi * 16 + r15) * 128 + ((ks * 64 + kh * 16) ^ rsw));
      #pragma unroll
      for (int ni = 0; ni < 4; ++ni){
        s8v bf = *(const s8v*)(BB + (wn + ni * 16 + r15) * 128 + ((ks * 64 + kh * 16) ^ rsw));
        #pragma unroll
        for (int mi = 0; mi < 4; ++mi)
          acc[mi][ni] = mfma16(af[mi], bf, acc[mi][ni]);
      }
    }
    __builtin_amdgcn_s_barrier();
  }

  #pragma unroll
  for (int mi = 0; mi < 4; ++mi){
    #pragma unroll
    for (int ni = 0; ni < 4; ++ni){
      #pragma unroll
      for (int j = 0; j < 4; ++j){
        float v = acc[mi][ni][j];
        int m = m0 + wm + mi * 16 + kh * 4 + j;
        int n = n0 + wn + ni * 16 + r15;
        if (EPI == 4){ // f32 final output [M][HID]
          ((float*)out0)[(size_t)m * HHID + n] = v;
        }
      }
    }
  }
}

// ---------------- GEMM v3: 256x256 4-phase template (T3+T4+T5) ----------------
template<int EPI>
__global__ __launch_bounds__(512, 1) void k_gemm8(
    const US* __restrict__ A, const US* __restrict__ Bt,
    void* __restrict__ out0, void* __restrict__ out1,
    void* __restrict__ out2, void* __restrict__ out3,
    int Kdim, int Ndim)
{
  __shared__ US As[2][256 * 64];   // 64 KB
  __shared__ US Bs[2][256 * 64];   // 64 KB
  const int tid = threadIdx.x, lane = tid & 63, w = tid >> 6;
  const int r15 = lane & 15, kh = lane >> 4;
  const int gx = gridDim.x;
  const int flat = blockIdx.y * gx + blockIdx.x;
  const int cpx = (gx * gridDim.y) >> 3;
  const int swz = (flat & 7) * cpx + (flat >> 3);
  const int m0 = (swz / gx) * 256, n0 = (swz % gx) * 256;
  const int wmL = (w >> 2) * 128, wnL = (w & 3) * 64;
  const int rsw = (r15 & 7) << 4;
  const int nt = Kdim >> 6;

  f4v acc[8][4] = {};
  s8v bf[4][2];

  auto STAGE_A = [&](int t, int par, int half){   // 2 gloads/thread
    int tt = (t < nt) ? t : (nt - 1);
    #pragma unroll
    for (int j = 0; j < 2; ++j){
      int c = j * 512 + tid;
      int row = c >> 3, ch = c & 7;
      gload_lds16((const char*)A + ((size_t)(m0 + half * 128 + row) * Kdim + tt * 64) * 2 + ((ch * 16) ^ ((row & 7) << 4)),
                  (char*)As[par] + half * 16384 + c * 16);
    }
  };
  auto STAGE_B = [&](int t, int par, int half){
    int tt = (t < nt) ? t : (nt - 1);
    #pragma unroll
    for (int j = 0; j < 2; ++j){
      int c = j * 512 + tid;
      int row = c >> 3, ch = c & 7;
      gload_lds16((const char*)Bt + ((size_t)(n0 + half * 128 + row) * Kdim + tt * 64) * 2 + ((ch * 16) ^ ((row & 7) << 4)),
                  (char*)Bs[par] + half * 16384 + c * 16);
    }
  };

  // ---- prologue: B(t0), A(t0), B(t1) -> queue 12 loads; land first 8
  STAGE_B(0, 0, 0); STAGE_B(0, 0, 1);
  STAGE_A(0, 0, 0); STAGE_A(0, 0, 1);
  STAGE_B(1, 1, 0); STAGE_B(1, 1, 1);
  asm volatile("s_waitcnt vmcnt(4)" ::: "memory");
  __builtin_amdgcn_s_barrier();

  const int nk2 = nt >> 1;
  for (int i = 0; i < nk2; ++i){
    const int t0 = 2 * i, t1 = 2 * i + 1;
    #pragma unroll
    for (int par = 0; par < 2; ++par){
      #pragma unroll
      for (int q = 0; q < 2; ++q){
        if (q == 0){
          #pragma unroll
          for (int ni = 0; ni < 4; ++ni)
            #pragma unroll
            for (int kk = 0; kk < 2; ++kk)
              bf[ni][kk] = *(const s8v*)((const char*)Bs[par] + (wnL + ni * 16 + r15) * 128 + ((kk * 64 + kh * 16) ^ rsw));
        }
        s8v af[4][2];
        #pragma unroll
        for (int m2 = 0; m2 < 4; ++m2)
          #pragma unroll
          for (int kk = 0; kk < 2; ++kk)
            af[m2][kk] = *(const s8v*)((const char*)As[par] + (wmL + (q * 4 + m2) * 16 + r15) * 128 + ((kk * 64 + kh * 16) ^ rsw));
        if (par == 0 && q == 0){ STAGE_A(t1, 1, 0); STAGE_A(t1, 1, 1); }
        else if (par == 0 && q == 1){ STAGE_B(t0 + 2, 0, 0); STAGE_B(t0 + 2, 0, 1); }
        else if (par == 1 && q == 0){ STAGE_A(t0 + 2, 0, 0); STAGE_A(t0 + 2, 0, 1); }
        else                        { STAGE_B(t1 + 2, 1, 0); STAGE_B(t1 + 2, 1, 1); }
        __builtin_amdgcn_s_barrier();
        __builtin_amdgcn_sched_barrier(0);
        __builtin_amdgcn_s_setprio(1);
        #pragma unroll
        for (int m2 = 0; m2 < 4; ++m2)
          #pragma unroll
          for (int ni = 0; ni < 4; ++ni)
            #pragma unroll
            for (int kk = 0; kk < 2; ++kk)
              acc[q * 4 + m2][ni] = mfma16(af[m2][kk], bf[ni][kk], acc[q * 4 + m2][ni]);
        __builtin_amdgcn_s_setprio(0);
        if (q == 1){ asm volatile("s_waitcnt vmcnt(4)" ::: "memory"); }
        __builtin_amdgcn_s_barrier();
      }
    }
  }

  // ---- epilogue
  #pragma unroll
  for (int mi = 0; mi < 8; ++mi){
    #pragma unroll
    for (int ni = 0; ni < 4; ++ni){
      #pragma unroll
      for (int j = 0; j < 4; ++j){
        float v = acc[mi][ni][j];
        int m = m0 + wmL + mi * 16 + kh * 4 + j;
        int n = n0 + wnL + ni * 16 + r15;
        if (EPI == 3){ // kv: k_nope -> knbuf [bh][s][128], v -> vbuf
          int b = m >> 11, s = m & 2047;
          int h = n >> 8, r = n & 255;
          if (r < 128)
            ((US*)out0)[((size_t)(b * HH + h) * HS + s) * HHD + r] = f2b(v);
          else
            ((US*)out1)[((size_t)(b * HH + h) * HS + s) * HHD + (r - 128)] = f2b(v);
        } else { // EPI==5: merged: q_nope | q_rope | latent | k_rope
          int b = m >> 11, s = m & 2047;
          if (n < 2048){
            int h = n >> 7, d = n & 127;
            ((US*)out0)[((size_t)(b * HH + h) * HS + s) * HAD + d] = f2b(v);
          } else if (n < 3072){
            int dd2 = n - 2048;
            int h = dd2 >> 6, dd = dd2 & 63;
            float partner = acc[mi][ni ^ 2][j];
            float2 cs = ((const float2*)out1)[s * 32 + (dd & 31)];
            float o = (dd < 32) ? (v * cs.x - partner * cs.y) : (v * cs.x + partner * cs.y);
            ((US*)out0)[((size_t)(b * HH + h) * HS + s) * HAD + HHD + dd] = f2b(o);
          } else if (n < 3584){
            ((US*)out2)[(size_t)m * HLD + (n - 3072)] = f2b(v);
          } else if (n < 3648){ // k_rope: RoPE, ONE shared copy
            int dd = n - 3584;
            float partner = acc[mi][ni ^ 2][j];
            float2 cs = ((const float2*)out1)[s * 32 + (dd & 31)];
            float o = (dd < 32) ? (v * cs.x - partner * cs.y) : (v * cs.x + partner * cs.y);
            ((US*)out3)[(size_t)m * HRD + dd] = f2b(o);
          } // n >= 3648: pad, drop
        }
      }
    }
  }
}

// ---------------- causal flash attention (R15-exact: KVBLK=64, 80KB, vmcnt(10)) ----
__global__ __launch_bounds__(256, 2) void k_attn(
    const US* __restrict__ qbuf, const US* __restrict__ knbuf,
    const US* __restrict__ krbuf, const US* __restrict__ vT,
    US* __restrict__ attnb)
{
  __shared__ US Ks[2][64 * 192];   // [kv][192] packed, byte ^= (kv&7)<<4   (48 KB)
  __shared__ US Vs[2][128 * 64];   // [d][64]  packed, byte ^= (d&7)<<4     (32 KB)

  const int tid = threadIdx.x, lane = tid & 63, w = tid >> 6;
  const int l31 = lane & 31, hi = lane >> 5;
  const int bid = blockIdx.x;           // bh = bid&31 -> XCD = bh&7 (K/V L2 locality)
  const int bh = bid & 31, b = bh >> 4, head = bh & 15;
  // LPT: first 256 blocks long (u=15..8), second 256 short (u=0..7)
  const int u = (bid < 256) ? (15 - (bid >> 5)) : ((bid - 256) >> 5);
  const int q0 = u * 128;
  const int qw0 = q0 + w * 32;                       // wave's first q row
  const int qrow = qw0 + l31;                        // this lane's q row
  const int sw = (l31 & 7) << 4;                     // XOR swizzle for K/V reads

  const char* qb = (const char*)(qbuf + (size_t)bh * HS * HAD);
  const char* kn = (const char*)(knbuf + (size_t)bh * HS * HHD);
  const char* kr = (const char*)(krbuf + (size_t)b * HS * HRD);
  const char* vb = (const char*)(vT   + (size_t)bh * HHD * HS);

  // Q fragments (B-operand): col = lane&31 = q, k = hi*8 + j
  s8v qf[12];
  {
    const char* qr = qb + (size_t)qrow * 384;
    #pragma unroll
    for (int ks = 0; ks < 12; ++ks)
      qf[ks] = *(const s8v*)(qr + ks * 32 + hi * 16);
  }

  // stage one 64-KV tile into buffer bb (10 global_load_lds per lane)
  auto STAGE = [&](int tt, int bb){
    const int k0s = tt * 64;
    #pragma unroll
    for (int j = 0; j < 6; ++j){               // K: 64 rows x 24 16B-chunks = 1536
      int c = j * 256 + tid;
      int row = c / 24, cc = c - row * 24;
      int xsw = (row & 7) << 4;
      const char* src = (cc < 16)
          ? kn + (size_t)(k0s + row) * 256 + ((cc * 16) ^ xsw)
          : kr + (size_t)(k0s + row) * 128 + (((cc - 16) * 16) ^ xsw);
      gload_lds16(src, (char*)Ks[bb] + (j * 4 + w) * 1024);
    }
    #pragma unroll
    for (int j = 0; j < 4; ++j){               // V^T: 128 rows x 8 chunks = 1024
      int c = j * 256 + tid;
      int d = c >> 3, colD = (c & 7) * 16;
      gload_lds16(vb + (size_t)d * (HS * 2) + (size_t)k0s * 2 + (colD ^ ((d & 7) << 4)),
                  (char*)Vs[bb] + (j * 4 + w) * 1024);
    }
  };

  f16v acc_o[4] = {};       // O: rows q=crow(r,hi), cols d = db*32 + l31
  float mraw = -3e38f, lsum = 0.f;

  const int nt = (q0 + 128) >> 6;
  STAGE(0, 0);
  for (int t = 0; t < nt; ++t){
    if (t + 1 < nt){
      STAGE(t + 1, (t + 1) & 1);
      asm volatile("s_waitcnt vmcnt(10)" ::: "memory");  // tile t landed; t+1 in flight
    } else {
      asm volatile("s_waitcnt vmcnt(0)" ::: "memory");
    }
    __builtin_amdgcn_s_barrier();
    __builtin_amdgcn_sched_barrier(0);

    const int k0 = t * 64;
    if (k0 <= qw0 + 31){     // wave-uniform: skip fully-masked tiles
      const char* KB = (const char*)Ks[t & 1];
      const char* VB = (const char*)Vs[t & 1];
      // ---- QK^T (swapped): S^T[kv][q], A=K from LDS, B=Q regs
      f16v sacc[2] = {};
      __builtin_amdgcn_s_setprio(1);
      #pragma unroll
      for (int ks = 0; ks < 12; ++ks){
        #pragma unroll
        for (int ni = 0; ni < 2; ++ni){
          s8v kf = *(const s8v*)(KB + (ni * 32 + l31) * 384 + ((ks * 32 + hi * 16) ^ sw));
          sacc[ni] = mfma32(kf, qf[ks], sacc[ni]);
        }
      }
      __builtin_amdgcn_s_setprio(0);

      // ---- mask + tile max (in-lane; lane owns q-row qrow)
      const bool need_mask = (k0 + 63 > qrow);
      float mx = -3e38f;
      #pragma unroll
      for (int ni = 0; ni < 2; ++ni){
        #pragma unroll
        for (int r = 0; r < 16; ++r){
          float s = sacc[ni][r];
          if (need_mask){
            int kv = k0 + ni * 32 + (r & 3) + 8 * (r >> 2) + 4 * hi;
            if (kv > qrow) s = -3e38f;
            sacc[ni][r] = s;
          }
          mx = fmaxf(mx, s);
        }
      }
      mx = fmaxf(mx, __shfl_xor(mx, 32));

      // ---- defer-max (T13)
      float scl = 1.0f;
      if (__any(mx > mraw + 76.8f)){           // 76.8 = 8 / (SCALE*log2e)
        float mnew = fmaxf(mraw, mx);
        scl = EXP2F((mraw - mnew) * C1_SCALE_LOG2E);
        mraw = mnew;
        #pragma unroll
        for (int r = 0; r < 16; ++r){
          float sb = __shfl(scl, (r & 3) + 8 * (r >> 2) + 4 * hi);
          #pragma unroll
          for (int db = 0; db < 4; ++db)
            acc_o[db][r] *= sb;
        }
      }

      // ---- exp + row-sum
      float m2 = mraw * C1_SCALE_LOG2E;
      float rs = 0.f;
      #pragma unroll
      for (int ni = 0; ni < 2; ++ni){
        #pragma unroll
        for (int r = 0; r < 16; ++r){
          float p = EXP2F(fmaf(sacc[ni][r], C1_SCALE_LOG2E, -m2));
          sacc[ni][r] = p;
          rs += p;
        }
      }
      rs += __shfl_xor(rs, 32);
      lsum = lsum * scl + rs;

      // ---- P -> bf16 A-frags in-register: 16 cvt_pk + 8 permlane32_swap
      union PU { s8v v; unsigned u[4]; } pa[4];
      #pragma unroll
      for (int ni = 0; ni < 2; ++ni){
        #pragma unroll
        for (int g = 0; g < 2; ++g){
          unsigned a0, a1, b0, b1;
          const int rb = g * 8;
          asm("v_cvt_pk_bf16_f32 %0, %1, %2" : "=v"(a0) : "v"(sacc[ni][rb + 0]), "v"(sacc[ni][rb + 1]));
          asm("v_cvt_pk_bf16_f32 %0, %1, %2" : "=v"(a1) : "v"(sacc[ni][rb + 2]), "v"(sacc[ni][rb + 3]));
          asm("v_cvt_pk_bf16_f32 %0, %1, %2" : "=v"(b0) : "v"(sacc[ni][rb + 4]), "v"(sacc[ni][rb + 5]));
          asm("v_cvt_pk_bf16_f32 %0, %1, %2" : "=v"(b1) : "v"(sacc[ni][rb + 6]), "v"(sacc[ni][rb + 7]));
          asm("v_permlane32_swap_b32 %0, %1" : "+v"(a0), "+v"(b0));
          asm("v_permlane32_swap_b32 %0, %1" : "+v"(a1), "+v"(b1));
          pa[ni * 2 + g].u[0] = a0; pa[ni * 2 + g].u[1] = a1;
          pa[ni * 2 + g].u[2] = b0; pa[ni * 2 + g].u[3] = b1;
        }
      }

      // ---- PV: O += P * V, B-frags from swizzled Vs
      __builtin_amdgcn_s_setprio(1);
      #pragma unroll
      for (int ks2 = 0; ks2 < 4; ++ks2){
        #pragma unroll
        for (int db = 0; db < 4; ++db){
          s8v vf = *(const s8v*)(VB + (db * 32 + l31) * 128 + ((ks2 * 32 + hi * 16) ^ sw));
          acc_o[db] = mfma32(pa[ks2].v, vf, acc_o[db]);
        }
      }
      __builtin_amdgcn_s_setprio(0);
    }
    __builtin_amdgcn_s_barrier();
  }

  // ---- epilogue: normalize by 1/l (broadcast to crow layout via shfl), store
  float linv = 1.0f / lsum;
  #pragma unroll
  for (int r = 0; r < 16; ++r){
    int crow = (r & 3) + 8 * (r >> 2) + 4 * hi;
    float lb = __shfl(linv, crow);
    int qq = qw0 + crow;
    US* dst = attnb + (size_t)(b * HS + qq) * (HH * HHD) + head * HHD;
    #pragma unroll
    for (int db = 0; db < 4; ++db)
      dst[db * 32 + l31] = f2b(acc_o[db][r] * lb);
  }
}

extern "C" void kernel_launch(void* const* d_in, const int* in_sizes, int n_in,
                              void* d_out, int out_size, void* d_ws, size_t ws_size,
                              hipStream_t stream)
{
  (void)in_sizes; (void)n_in; (void)out_size; (void)ws_size;
  const float* x        = (const float*)d_in[0];
  const float* wq       = (const float*)d_in[1];
  const float* wq_rope  = (const float*)d_in[2];
  const float* wkv_down = (const float*)d_in[3];
  const float* wkv_up   = (const float*)d_in[4];
  const float* wk_rope  = (const float*)d_in[5];
  const float* wo       = (const float*)d_in[6];

  char* ws = (char*)d_ws;
  size_t off = 0;
  auto alloc = [&](size_t bytes)->void*{ void* p = ws + off; off += (bytes + 255) & ~(size_t)255; return p; };

  US* xb     = (US*)alloc((size_t)HM * HHID * 2);        // 16 MB (aliased as attnb later)
  // wqT/wqrT/wkvdT/wkrT/pad contiguous -> one merged B^T [3840][2048] (incl 192 pad rows)
  US* wqT    = (US*)alloc((size_t)2048 * 2048 * 2);
  US* wqrT   = (US*)alloc((size_t)1024 * 2048 * 2);
  US* wkvdT  = (US*)alloc((size_t)512 * 2048 * 2);
  US* wkrT   = (US*)alloc((size_t)64 * 2048 * 2);
  US* wkrPad = (US*)alloc((size_t)192 * 2048 * 2);       // zeroed pad rows 3648..3839
  US* wkvuT  = (US*)alloc((size_t)4096 * 512 * 2);
  US* woT    = (US*)alloc((size_t)2048 * 2048 * 2);
  US* qbuf   = (US*)alloc((size_t)32 * HS * HAD * 2);
  US* knbuf  = (US*)alloc((size_t)32 * HS * HHD * 2);    // k_nope per-head
  US* krbuf  = (US*)alloc((size_t)HB * HS * HRD * 2);    // k_rope shared (0.5 MB)
  US* vbuf   = (US*)alloc((size_t)32 * HS * HHD * 2);
  US* vTb    = (US*)alloc((size_t)32 * HS * HHD * 2);
  US* latent = (US*)alloc((size_t)HM * HLD * 2);
  float2* tab = (float2*)alloc((size_t)HS * 32 * 8);
  US* attnb = xb;   // xb dead after merged projection; reuse

  dim3 tb(256);
  dim3 t328(32, 8);

  hipMemsetAsync(wkrPad, 0, (size_t)192 * 2048 * 2, stream);
  k_cast<<<dim3(8192), tb, 0, stream>>>(x, xb, HM * HHID);
  k_rope_tab<<<dim3(256), tb, 0, stream>>>(tab);
  // fused weight prep: 4096+2048+1024+128+2048+4096 = 13440 tile-blocks
  k_prep<<<dim3(13440), tb, 0, stream>>>(wq, wq_rope, wkv_down, wk_rope, wkv_up, wo,
                                         wqT, wqrT, wkvdT, wkrT, wkvuT, woT);

  // merged x-projections: [4096,2048] x [3840,2048]^T (4-phase 256^2)
  k_gemm8<5><<<dim3(15, 16), dim3(512), 0, stream>>>(xb, wqT, (void*)qbuf, (void*)tab, (void*)latent, (void*)krbuf, 2048, 3840);
  // kv-up: [4096,512] x [4096,512]^T (4-phase 256^2)
  k_gemm8<3><<<dim3(16, 16), dim3(512), 0, stream>>>(latent, wkvuT, (void*)knbuf, (void*)vbuf, (void*)nullptr, (void*)nullptr, 512, 4096);
  k_transpose_v<<<dim3(64, 4, 32), t328, 0, stream>>>(vbuf, vTb);
  k_attn<<<dim3(512), tb, 0, stream>>>(qbuf, knbuf, krbuf, vTb, attnb);
  k_gemm2<4><<<dim3(16, 32), tb, 0, stream>>>(attnb, woT, d_out, (void*)nullptr, (void*)nullptr, (void*)nullptr, 2048, 2048);
}